// Round 8
// baseline (179.167 us; speedup 1.0000x reference)
//
#include <hip/hip_runtime.h>
#include <hip/hip_bf16.h>
#include <math.h>

// Problem constants
#define B_  64
#define L_  512
#define D_  768
#define K_  6      // NUM_LABELS
#define P_  3      // POL_DIM

#define POOL_BLOCKS 192            // 16 b-groups x 12 j-groups
#define ATE_BLOCKS  1024           // 16/batch; block = 4 waves x 8 ranks

typedef float f4_t __attribute__((ext_vector_type(4)));

// ---- DPP wave64 sum (result valid in lane 63), VALU pipe only -------------
template <int CTRL, int ROWMASK>
__device__ __forceinline__ float dpp_add(float x) {
  int moved = __builtin_amdgcn_update_dpp(0, __float_as_int(x), CTRL, ROWMASK,
                                          0xf, false);
  return x + __int_as_float(moved);
}
__device__ __forceinline__ float wave_sum63(float x) {
  x = dpp_add<0x111, 0xf>(x);  // row_shr:1
  x = dpp_add<0x112, 0xf>(x);  // row_shr:2
  x = dpp_add<0x114, 0xf>(x);  // row_shr:4
  x = dpp_add<0x118, 0xf>(x);  // row_shr:8
  x = dpp_add<0x142, 0xa>(x);  // row_bcast:15
  x = dpp_add<0x143, 0xc>(x);  // row_bcast:31
  return x;                    // lane 63 = full 64-lane sum
}

// ---------------------------------------------------------------------------
// D1: fused kernel.
//  blockIdx < 192 : pool role: wave = (batch b, 64-j slice). Coalesced W
//                   columns, wave-uniform x reads, partial -> ws[jg][b][3].
//  blockIdx >=192 : ATE role: 8 compact rows/wave. KEY CHANGE vs R7: weights
//                   are loaded AT USE from L1 (18 KB, hot) instead of a
//                   72-VGPR hoisted array that spilled to scratch.
// ---------------------------------------------------------------------------
__global__ __launch_bounds__(256) void k_fused(
    const float* __restrict__ x, const int* __restrict__ valid,
    const float* __restrict__ w_cls, const float* __restrict__ b_cls,
    const float* __restrict__ w_pool, const float* __restrict__ b_pool,
    const float* __restrict__ w_apc, float* __restrict__ out,
    float* __restrict__ ws_apc) {
  const int wid = threadIdx.x >> 6;
  const int lane = threadIdx.x & 63;

  if (blockIdx.x < POOL_BLOCKS) {
    // ================= pool role: batch b, j-slice jg =================
    const int b = (blockIdx.x & 15) * 4 + wid;
    const int jg = blockIdx.x >> 4;          // 0..11
    const int j = jg * 64 + lane;

    const int4* vp = (const int4*)(valid + b * L_);
    const int4 va = vp[lane * 2];
    const int4 vb = vp[lane * 2 + 1];
    const int m8 = va.x | (va.y << 1) | (va.z << 2) | (va.w << 3) |
                   (vb.x << 4) | (vb.y << 5) | (vb.z << 6) | (vb.w << 7);
    int loc = m8 ? (8 * lane + __ffs(m8) - 1) : (1 << 30);
#pragma unroll
    for (int off = 32; off >= 1; off >>= 1) {
      const int o = __shfl_xor(loc, off, 64);
      loc = (o < loc) ? o : loc;
    }
    const int src = __builtin_amdgcn_readfirstlane(loc);

    float a0 = 0.f, a1 = 0.f, a2 = 0.f, a3 = 0.f;
    if (src < L_) {
      const float* xr = x + ((size_t)(b * L_ + src)) * D_;  // uniform base
      const float* wp = w_pool + j;                          // lane-coalesced
#pragma unroll 4
      for (int i = 0; i < D_; i += 4) {
        a0 += xr[i]     * wp[(size_t)i * D_];
        a1 += xr[i + 1] * wp[(size_t)(i + 1) * D_];
        a2 += xr[i + 2] * wp[(size_t)(i + 2) * D_];
        a3 += xr[i + 3] * wp[(size_t)(i + 3) * D_];
      }
    }
    const float val = tanhf((a0 + a1) + (a2 + a3) + b_pool[j]);

    float p0 = wave_sum63(val * w_apc[j * P_ + 0]);
    float p1 = wave_sum63(val * w_apc[j * P_ + 1]);
    float p2 = wave_sum63(val * w_apc[j * P_ + 2]);
    if (lane == 63) {
      float* d = ws_apc + (jg * B_ + b) * P_;
      d[0] = p0; d[1] = p1; d[2] = p2;
    }
    return;
  }

  // ================= ATE role (barrier-free waves, low VGPR) ==============
  __shared__ int smap[4 * 8];  // 8 ranks per wave

  const int ab = blockIdx.x - POOL_BLOCKS;
  const int b = ab >> 4;                         // 16 blocks per batch
  const int jb = ((ab & 15) << 5) + (wid << 3);  // this wave's first rank

  const int4* vp = (const int4*)(valid + b * L_);
  const int4 va = vp[lane * 2];
  const int4 vb2 = vp[lane * 2 + 1];
  const int v[8] = {va.x, va.y, va.z, va.w, vb2.x, vb2.y, vb2.z, vb2.w};
  int cnt = 0;
#pragma unroll
  for (int t = 0; t < 8; ++t) cnt += v[t];
  int pre = cnt;
#pragma unroll
  for (int off = 1; off < 64; off <<= 1) {
    const int n = __shfl_up(pre, off, 64);
    pre += (lane >= off) ? n : 0;
  }
  pre -= cnt;                                  // exclusive prefix
  const int nvalid = __shfl(pre + cnt, 63);

  const float bc0 = b_cls[0], bc1 = b_cls[1], bc2 = b_cls[2];
  const float bc3 = b_cls[3], bc4 = b_cls[4], bc5 = b_cls[5];
  const f4_t bias0 = {bc0, bc1, bc2, bc3};
  const f4_t bias1 = {bc4, bc5, bc0, bc1};
  const f4_t bias2 = {bc2, bc3, bc4, bc5};

  float* orow = out + ((size_t)(b * L_ + jb)) * K_;  // 8-row slab

  if (jb >= nvalid) {
    if (lane < 12) {
      const int m = lane % 3;
      const f4_t s = (m == 0) ? bias0 : ((m == 1) ? bias1 : bias2);
      ((f4_t*)orow)[lane] = s;
    }
    return;
  }

  // rank -> token map for this wave's 8 ranks (same-wave LDS, no barrier)
  if (lane < 8) smap[wid * 8 + lane] = -1;
  int run = pre;
#pragma unroll
  for (int t = 0; t < 8; ++t) {
    if (v[t]) {
      const int rel = run - jb;
      if ((unsigned)rel < 8u) smap[wid * 8 + rel] = 8 * lane + t;
      ++run;
    }
  }
  const int smap_reg = smap[wid * 8 + (lane & 7)];

  const f4_t* w4 = (const f4_t*)w_cls;  // lane's slice base: w4 + 384c + 6*lane
  const float* xb = x + (size_t)b * L_ * D_;

#pragma unroll
  for (int pp = 0; pp < 4; ++pp) {
    const int r0 = jb + 2 * pp;
    const int src0 = __builtin_amdgcn_readlane(smap_reg, 2 * pp);
    const int src1 = __builtin_amdgcn_readlane(smap_reg, 2 * pp + 1);
    f4_t* o = (f4_t*)(out + ((size_t)(b * L_ + r0)) * K_);

    if (src0 < 0) {
      if (lane == 63) { o[0] = bias0; o[1] = bias1; o[2] = bias2; }
      continue;
    }
    const int s1 = (src1 >= 0) ? src1 : src0;
    const f4_t* x0 = (const f4_t*)(xb + (size_t)src0 * D_);
    const f4_t* x1 = (const f4_t*)(xb + (size_t)s1 * D_);

    float a0[K_] = {0.f, 0.f, 0.f, 0.f, 0.f, 0.f};
    float a1[K_] = {0.f, 0.f, 0.f, 0.f, 0.f, 0.f};
#pragma unroll
    for (int c = 0; c < 3; ++c) {
      const f4_t xv0 = x0[lane + 64 * c];
      const f4_t xv1 = x1[lane + 64 * c];
      const f4_t* wp = w4 + 384 * c + 6 * lane;  // L1-hot (18 KB total)
#pragma unroll
      for (int jx = 0; jx < 6; ++jx) {
        const f4_t wv = wp[jx];  // loaded at use -> no 72-reg hoist, no spill
#pragma unroll
        for (int e = 0; e < 4; ++e) {
          const int idx = 4 * jx + e;           // 0..23
          const int i = idx / K_, k = idx % K_; // d-elem i, label k
          a0[k] += xv0[i] * wv[e];
          a1[k] += xv1[i] * wv[e];
        }
      }
    }
#pragma unroll
    for (int k = 0; k < K_; ++k) {
      a0[k] = wave_sum63(a0[k]);
      a1[k] = wave_sum63(a1[k]);
    }
    if (lane == 63) {
      const bool ok1 = (src1 >= 0);
      const f4_t o0 = {a0[0] + bc0, a0[1] + bc1, a0[2] + bc2, a0[3] + bc3};
      const f4_t o1 = {a0[4] + bc4, a0[5] + bc5,
                       (ok1 ? a1[0] : 0.f) + bc0, (ok1 ? a1[1] : 0.f) + bc1};
      const f4_t o2 = {(ok1 ? a1[2] : 0.f) + bc2, (ok1 ? a1[3] : 0.f) + bc3,
                       (ok1 ? a1[4] : 0.f) + bc4, (ok1 ? a1[5] : 0.f) + bc5};
      o[0] = o0; o[1] = o1; o[2] = o2;
    }
  }
}

// ---------------------------------------------------------------------------
// D2: APC finalize — sum 12 j-group partials per (b,c), add bias.
// ---------------------------------------------------------------------------
__global__ __launch_bounds__(192) void k_apc(
    const float* __restrict__ ws_apc, const float* __restrict__ b_apc,
    float* __restrict__ out_apc) {
  const int t = threadIdx.x;  // 0..191 -> (b, c)
  float s = 0.f;
#pragma unroll
  for (int g = 0; g < 12; ++g) s += ws_apc[g * (B_ * P_) + t];
  out_apc[t] = s + b_apc[t % P_];
}

// ---------------------------------------------------------------------------
extern "C" void kernel_launch(void* const* d_in, const int* in_sizes, int n_in,
                              void* d_out, int out_size, void* d_ws, size_t ws_size,
                              hipStream_t stream) {
  const float* x      = (const float*)d_in[0];  // [B,L,D]
  const int*   valid  = (const int*)d_in[1];    // [B,L]
  const float* w_cls  = (const float*)d_in[2];  // [D,K]
  const float* b_cls  = (const float*)d_in[3];  // [K]
  const float* w_pool = (const float*)d_in[4];  // [D,D]
  const float* b_pool = (const float*)d_in[5];  // [D]
  const float* w_apc  = (const float*)d_in[6];  // [D,P]
  const float* b_apc  = (const float*)d_in[7];  // [P]

  float* out     = (float*)d_out;
  float* out_apc = out + (size_t)B_ * L_ * K_;
  float* ws_apc  = (float*)d_ws;                // 12*64*3 floats = 9216 B

  k_fused<<<POOL_BLOCKS + ATE_BLOCKS, 256, 0, stream>>>(
      x, valid, w_cls, b_cls, w_pool, b_pool, w_apc, out, ws_apc);
  k_apc<<<1, 192, 0, stream>>>(ws_apc, b_apc, out_apc);
}

// Round 9
// 166.398 us; speedup vs baseline: 1.0767x; 1.0767x over previous
//
#include <hip/hip_runtime.h>
#include <hip/hip_bf16.h>
#include <math.h>

// Problem constants
#define B_  64
#define L_  512
#define D_  768
#define K_  6      // NUM_LABELS
#define P_  3      // POL_DIM

#define POOL_BLOCKS 192            // 16 b-groups x 12 j-groups (R7 proven)
#define ATE_BLOCKS  1024           // 16/batch; block = 4 waves x 8 ranks

typedef float f4_t __attribute__((ext_vector_type(4)));

// ---- DPP wave64 sum (result valid in lane 63), VALU pipe only -------------
template <int CTRL, int ROWMASK>
__device__ __forceinline__ float dpp_add(float x) {
  int moved = __builtin_amdgcn_update_dpp(0, __float_as_int(x), CTRL, ROWMASK,
                                          0xf, false);
  return x + __int_as_float(moved);
}
__device__ __forceinline__ float wave_sum63(float x) {
  x = dpp_add<0x111, 0xf>(x);  // row_shr:1
  x = dpp_add<0x112, 0xf>(x);  // row_shr:2
  x = dpp_add<0x114, 0xf>(x);  // row_shr:4
  x = dpp_add<0x118, 0xf>(x);  // row_shr:8
  x = dpp_add<0x142, 0xa>(x);  // row_bcast:15
  x = dpp_add<0x143, 0xc>(x);  // row_bcast:31
  return x;                    // lane 63 = full 64-lane sum
}

// ---------------------------------------------------------------------------
// D1: fused kernel.
//  blockIdx < 192 : pool role (unchanged from R7-best).
//  blockIdx >=192 : ATE role. KEY CHANGE: W_cls^T staged in LDS (coalesced
//                   global reads, once/block); main-loop weight reads are
//                   ds_read_b128 at 16B lane stride (conflict-free) instead
//                   of 96B-stride global loads that serialized the L1 port.
//                   All 8 rows per wave in ONE K-pass (18 weight reads/wave).
// ---------------------------------------------------------------------------
__global__ __launch_bounds__(256, 2) void k_fused(
    const float* __restrict__ x, const int* __restrict__ valid,
    const float* __restrict__ w_cls, const float* __restrict__ b_cls,
    const float* __restrict__ w_pool, const float* __restrict__ b_pool,
    const float* __restrict__ w_apc, float* __restrict__ out,
    float* __restrict__ ws_apc) {
  const int wid = threadIdx.x >> 6;
  const int lane = threadIdx.x & 63;

  if (blockIdx.x < POOL_BLOCKS) {
    // ================= pool role: batch b, j-slice jg (R7) =================
    const int b = (blockIdx.x & 15) * 4 + wid;
    const int jg = blockIdx.x >> 4;          // 0..11
    const int j = jg * 64 + lane;

    const int4* vp = (const int4*)(valid + b * L_);
    const int4 va = vp[lane * 2];
    const int4 vb = vp[lane * 2 + 1];
    const int m8 = va.x | (va.y << 1) | (va.z << 2) | (va.w << 3) |
                   (vb.x << 4) | (vb.y << 5) | (vb.z << 6) | (vb.w << 7);
    int loc = m8 ? (8 * lane + __ffs(m8) - 1) : (1 << 30);
#pragma unroll
    for (int off = 32; off >= 1; off >>= 1) {
      const int o = __shfl_xor(loc, off, 64);
      loc = (o < loc) ? o : loc;
    }
    const int src = __builtin_amdgcn_readfirstlane(loc);

    float a0 = 0.f, a1 = 0.f, a2 = 0.f, a3 = 0.f;
    if (src < L_) {
      const float* xr = x + ((size_t)(b * L_ + src)) * D_;  // uniform base
      const float* wp = w_pool + j;                          // lane-coalesced
#pragma unroll 4
      for (int i = 0; i < D_; i += 4) {
        a0 += xr[i]     * wp[(size_t)i * D_];
        a1 += xr[i + 1] * wp[(size_t)(i + 1) * D_];
        a2 += xr[i + 2] * wp[(size_t)(i + 2) * D_];
        a3 += xr[i + 3] * wp[(size_t)(i + 3) * D_];
      }
    }
    const float val = tanhf((a0 + a1) + (a2 + a3) + b_pool[j]);

    float p0 = wave_sum63(val * w_apc[j * P_ + 0]);
    float p1 = wave_sum63(val * w_apc[j * P_ + 1]);
    float p2 = wave_sum63(val * w_apc[j * P_ + 2]);
    if (lane == 63) {
      float* d = ws_apc + (jg * B_ + b) * P_;
      d[0] = p0; d[1] = p1; d[2] = p2;
    }
    return;
  }

  // ================= ATE role =================
  __shared__ float swt[K_ * D_];  // 18 KB: W_cls^T [k][d]
  __shared__ int smap[4 * 8];     // 8 ranks per wave

  const int ab = blockIdx.x - POOL_BLOCKS;
  const int b = ab >> 4;                         // 16 blocks per batch
  const int jb = ((ab & 15) << 5) + (wid << 3);  // this wave's first rank

  // ---- stage W^T: coalesced float2 global reads, transposed LDS writes ----
  {
    const float2* wsrc = (const float2*)w_cls;  // 2304 float2
#pragma unroll
    for (int q = 0; q < 9; ++q) {
      const int m = threadIdx.x + 256 * q;
      const float2 w2 = wsrc[m];
      const int f0 = 2 * m;                     // flat = d*6 + k
      swt[(f0 % K_) * D_ + f0 / K_] = w2.x;
      const int f1 = f0 + 1;
      swt[(f1 % K_) * D_ + f1 / K_] = w2.y;
    }
  }

  // ---- per-wave scan of valid[b][:] ----
  const int4* vp = (const int4*)(valid + b * L_);
  const int4 va = vp[lane * 2];
  const int4 vb2 = vp[lane * 2 + 1];
  const int v[8] = {va.x, va.y, va.z, va.w, vb2.x, vb2.y, vb2.z, vb2.w};
  int cnt = 0;
#pragma unroll
  for (int t = 0; t < 8; ++t) cnt += v[t];
  int pre = cnt;
#pragma unroll
  for (int off = 1; off < 64; off <<= 1) {
    const int n = __shfl_up(pre, off, 64);
    pre += (lane >= off) ? n : 0;
  }
  pre -= cnt;                                  // exclusive prefix
  const int nvalid = __shfl(pre + cnt, 63);

  // rank -> token map for this wave's 8 ranks (same-wave LDS, in-order)
  if (lane < 8) smap[wid * 8 + lane] = -1;
  int run = pre;
#pragma unroll
  for (int t = 0; t < 8; ++t) {
    if (v[t]) {
      const int rel = run - jb;
      if ((unsigned)rel < 8u) smap[wid * 8 + rel] = 8 * lane + t;
      ++run;
    }
  }

  __syncthreads();  // ALL waves reach this (early-outs only after)

  const float bc0 = b_cls[0], bc1 = b_cls[1], bc2 = b_cls[2];
  const float bc3 = b_cls[3], bc4 = b_cls[4], bc5 = b_cls[5];

  if (jb >= nvalid) {
    // whole wave invalid: bulk bias fill of the 8-row slab
    const f4_t bias0 = {bc0, bc1, bc2, bc3};
    const f4_t bias1 = {bc4, bc5, bc0, bc1};
    const f4_t bias2 = {bc2, bc3, bc4, bc5};
    if (lane < 12) {
      const int m = lane % 3;
      const f4_t s = (m == 0) ? bias0 : ((m == 1) ? bias1 : bias2);
      ((f4_t*)(out + ((size_t)(b * L_ + jb)) * K_))[lane] = s;
    }
    return;
  }

  const int sm = smap[wid * 8 + (lane & 7)];
  int srcs[8];
#pragma unroll
  for (int r = 0; r < 8; ++r) srcs[r] = __builtin_amdgcn_readlane(sm, r);
  const int src0 = srcs[0];  // valid (jb < nvalid)

  const float* xb = x + (size_t)b * L_ * D_;
  const f4_t* swt4 = (const f4_t*)swt;

  float acc[8][K_];
#pragma unroll
  for (int r = 0; r < 8; ++r)
#pragma unroll
    for (int k = 0; k < K_; ++k) acc[r][k] = 0.f;

#pragma unroll
  for (int c = 0; c < 3; ++c) {
    const int dl = lane + 64 * c;  // f4 index within a 768-dim row
    f4_t xv[8];
#pragma unroll
    for (int r = 0; r < 8; ++r) {
      const int s = (srcs[r] >= 0) ? srcs[r] : src0;
      xv[r] = __builtin_nontemporal_load((const f4_t*)(xb + (size_t)s * D_) + dl);
    }
#pragma unroll
    for (int k = 0; k < K_; ++k) {
      const f4_t wv = swt4[k * (D_ / 4) + dl];  // ds_read_b128, conflict-free
#pragma unroll
      for (int r = 0; r < 8; ++r) {
        acc[r][k] += xv[r][0] * wv[0] + xv[r][1] * wv[1] +
                     xv[r][2] * wv[2] + xv[r][3] * wv[3];
      }
    }
  }

#pragma unroll
  for (int r = 0; r < 8; ++r)
#pragma unroll
    for (int k = 0; k < K_; ++k) acc[r][k] = wave_sum63(acc[r][k]);

  if (lane == 63) {
    f4_t* o = (f4_t*)(out + ((size_t)(b * L_ + jb)) * K_);  // 48 floats
#pragma unroll
    for (int pp = 0; pp < 4; ++pp) {
      const bool ok0 = srcs[2 * pp] >= 0;
      const bool ok1 = srcs[2 * pp + 1] >= 0;
      float s0[K_], s1[K_];
#pragma unroll
      for (int k = 0; k < K_; ++k) {
        s0[k] = ok0 ? acc[2 * pp][k] : 0.f;
        s1[k] = ok1 ? acc[2 * pp + 1][k] : 0.f;
      }
      const f4_t o0 = {s0[0] + bc0, s0[1] + bc1, s0[2] + bc2, s0[3] + bc3};
      const f4_t o1 = {s0[4] + bc4, s0[5] + bc5, s1[0] + bc0, s1[1] + bc1};
      const f4_t o2 = {s1[2] + bc2, s1[3] + bc3, s1[4] + bc4, s1[5] + bc5};
      o[3 * pp + 0] = o0;
      o[3 * pp + 1] = o1;
      o[3 * pp + 2] = o2;
    }
  }
}

// ---------------------------------------------------------------------------
// D2: APC finalize — sum 12 j-group partials per (b,c), add bias.
// ---------------------------------------------------------------------------
__global__ __launch_bounds__(192) void k_apc(
    const float* __restrict__ ws_apc, const float* __restrict__ b_apc,
    float* __restrict__ out_apc) {
  const int t = threadIdx.x;  // 0..191 -> (b, c)
  float s = 0.f;
#pragma unroll
  for (int g = 0; g < 12; ++g) s += ws_apc[g * (B_ * P_) + t];
  out_apc[t] = s + b_apc[t % P_];
}

// ---------------------------------------------------------------------------
extern "C" void kernel_launch(void* const* d_in, const int* in_sizes, int n_in,
                              void* d_out, int out_size, void* d_ws, size_t ws_size,
                              hipStream_t stream) {
  const float* x      = (const float*)d_in[0];  // [B,L,D]
  const int*   valid  = (const int*)d_in[1];    // [B,L]
  const float* w_cls  = (const float*)d_in[2];  // [D,K]
  const float* b_cls  = (const float*)d_in[3];  // [K]
  const float* w_pool = (const float*)d_in[4];  // [D,D]
  const float* b_pool = (const float*)d_in[5];  // [D]
  const float* w_apc  = (const float*)d_in[6];  // [D,P]
  const float* b_apc  = (const float*)d_in[7];  // [P]

  float* out     = (float*)d_out;
  float* out_apc = out + (size_t)B_ * L_ * K_;
  float* ws_apc  = (float*)d_ws;                // 12*64*3 floats = 9216 B

  k_fused<<<POOL_BLOCKS + ATE_BLOCKS, 256, 0, stream>>>(
      x, valid, w_cls, b_cls, w_pool, b_pool, w_apc, out, ws_apc);
  k_apc<<<1, 192, 0, stream>>>(ws_apc, b_apc, out_apc);
}